// Round 3
// baseline (315.431 us; speedup 1.0000x reference)
//
#include <hip/hip_runtime.h>

// Hamilton product of quaternions, layout (..., 4) = (w, x, y, z) contiguous.
// Shapes: q1, q2: (32, 4096, 64, 4) fp32 -> 8,388,608 quaternions (402.7 MB
// total traffic -> memory-bound, roofline ~64us @ 6.3 TB/s).
// One quaternion == one float4 (16 B/lane). 2 quats/thread/iter for deeper
// VMEM pipelining; capped grid + grid-stride per G11.

__device__ __forceinline__ float4 hprod(float4 a, float4 b) {
    float4 o;
    o.x = a.x * b.x - a.y * b.y - a.z * b.z - a.w * b.w;  // w
    o.y = a.x * b.y + a.y * b.x + a.z * b.w - a.w * b.z;  // x
    o.z = a.x * b.z - a.y * b.w + a.z * b.x + a.w * b.y;  // y
    o.w = a.x * b.w + a.y * b.z - a.z * b.y + a.w * b.x;  // z
    return o;
}

__global__ __launch_bounds__(256) void hamilton_kernel(
    const float4* __restrict__ q1,
    const float4* __restrict__ q2,
    float4* __restrict__ out,
    int n_quat)
{
    int nthreads = gridDim.x * blockDim.x;
    int tid = blockIdx.x * blockDim.x + threadIdx.x;

    // Main loop: 2 quats per thread per iteration, consecutive lanes touch
    // consecutive float4s in each half -> fully coalesced dwordx4.
    int n_pairs = n_quat >> 1;   // iterate over pairs: [i] and [i + n_pairs]
    for (int i = tid; i < n_pairs; i += nthreads) {
        float4 a0 = q1[i];
        float4 b0 = q2[i];
        float4 a1 = q1[i + n_pairs];
        float4 b1 = q2[i + n_pairs];
        out[i]           = hprod(a0, b0);
        out[i + n_pairs] = hprod(a1, b1);
    }

    // Tail (only if n_quat is odd — not the case here, but correct anyway).
    if ((n_quat & 1) && tid == 0) {
        int last = n_quat - 1;
        out[last] = hprod(q1[last], q2[last]);
    }
}

extern "C" void kernel_launch(void* const* d_in, const int* in_sizes, int n_in,
                              void* d_out, int out_size, void* d_ws, size_t ws_size,
                              hipStream_t stream)
{
    const float4* q1 = (const float4*)d_in[0];
    const float4* q2 = (const float4*)d_in[1];
    float4* out = (float4*)d_out;

    int n_quat = in_sizes[0] / 4;   // 33,554,432 / 4 = 8,388,608

    int block = 256;
    int max_blocks = 2048;          // 256 CUs x 8 blocks/CU
    int grid = ((n_quat >> 1) + block - 1) / block;
    if (grid > max_blocks) grid = max_blocks;
    if (grid < 1) grid = 1;

    hamilton_kernel<<<grid, block, 0, stream>>>(q1, q2, out, n_quat);
}